// Round 7
// baseline (177.631 us; speedup 1.0000x reference)
//
#include <hip/hip_runtime.h>
#include <stdint.h>

#define N_NODES 8192
#define IN_FEAT 512
#define OUT_FEAT 256
#define LOG2E 1.4426950408889634f

typedef __bf16 b16x8 __attribute__((ext_vector_type(8)));
typedef unsigned short u16x8v __attribute__((ext_vector_type(8)));
typedef float f32x4 __attribute__((ext_vector_type(4)));

static __device__ __forceinline__ unsigned short f2bf(float f) {
    union { float f; uint32_t u; } v; v.f = f;
    uint32_t r = v.u + 0x7FFFu + ((v.u >> 16) & 1u);
    return (unsigned short)(r >> 16);
}

// K0: Wt[c][k] = bf16(W[k][c])  (256 x 512)
__global__ __launch_bounds__(256) void k0_transpose_w(const float* __restrict__ W,
                                                      unsigned short* __restrict__ Wt) {
    int tid = blockIdx.x * 256 + threadIdx.x;
    int c = tid & (OUT_FEAT - 1);
    int k = tid >> 8;
    Wt[(size_t)c * IN_FEAT + k] = f2bf(W[(size_t)k * OUT_FEAT + c]);
}

// K1: h = X @ W via bf16 MFMA. Writes hTf in MFMA-B-fragment order:
// hTf[((chunk*16 + t)*64 + lane)*8 + e] = bf16(h[chunk*32 + (lane>>4)*8 + e][16t + (lane&15)])
__global__ __launch_bounds__(256) void k1_hgemm(const float* __restrict__ input,
                                                const unsigned short* __restrict__ Wt,
                                                const float* __restrict__ a_vec,
                                                unsigned short* __restrict__ hTf,
                                                float* __restrict__ s1_raw,
                                                float* __restrict__ s2_raw) {
    int tid = threadIdx.x;
    int lane = tid & 63;
    int c = lane & 15, g = lane >> 4;
    int r0 = blockIdx.x * 64 + (tid >> 6) * 16;
    f32x4 acc[16];
#pragma unroll
    for (int t = 0; t < 16; ++t) acc[t] = (f32x4){0.f, 0.f, 0.f, 0.f};
    const float* arow = input + (size_t)(r0 + c) * IN_FEAT;
#pragma unroll 1
    for (int kk = 0; kk < IN_FEAT / 32; ++kk) {
        int kb = kk * 32 + 8 * g;
        float4 x0 = *(const float4*)(arow + kb);
        float4 x1 = *(const float4*)(arow + kb + 4);
        u16x8v au;
        au[0] = f2bf(x0.x); au[1] = f2bf(x0.y); au[2] = f2bf(x0.z); au[3] = f2bf(x0.w);
        au[4] = f2bf(x1.x); au[5] = f2bf(x1.y); au[6] = f2bf(x1.z); au[7] = f2bf(x1.w);
        b16x8 af = __builtin_bit_cast(b16x8, au);
#pragma unroll
        for (int t = 0; t < 16; ++t) {
            b16x8 bf = __builtin_bit_cast(b16x8,
                *(const u16x8v*)(Wt + (size_t)(16 * t + c) * IN_FEAT + kb));
            acc[t] = __builtin_amdgcn_mfma_f32_16x16x32_bf16(af, bf, acc[t], 0, 0, 0);
        }
    }
    float a1v[16], a2v[16];
#pragma unroll
    for (int t = 0; t < 16; ++t) {
        a1v[t] = a_vec[16 * t + c];
        a2v[t] = a_vec[OUT_FEAT + 16 * t + c];
    }
#pragma unroll
    for (int r = 0; r < 4; ++r) {
        float s1p = 0.f, s2p = 0.f;
#pragma unroll
        for (int t = 0; t < 16; ++t) { s1p += acc[t][r] * a1v[t]; s2p += acc[t][r] * a2v[t]; }
#pragma unroll
        for (int m = 1; m <= 8; m <<= 1) { s1p += __shfl_xor(s1p, m); s2p += __shfl_xor(s2p, m); }
        if (c == 0) {
            int row = r0 + 4 * g + r;
            s1_raw[row] = s1p;
            s2_raw[row] = s2p;
        }
    }
    int chunk = r0 >> 5;
    int lp = ((r0 & 16) >> 3) + (g >> 1);
    int e0 = 4 * (g & 1);
#pragma unroll
    for (int t = 0; t < 16; ++t) {
        ushort4 pk;
        pk.x = f2bf(acc[t][0]); pk.y = f2bf(acc[t][1]);
        pk.z = f2bf(acc[t][2]); pk.w = f2bf(acc[t][3]);
        *(ushort4*)(hTf + ((size_t)(chunk * 16 + t) * 64 + lp * 16 + c) * 8 + e0) = pk;
    }
}

// K2: M2 = max(s2); per-row constants a_row=(s1-m)*K, m8=-0.8*m*K; s2k=s2*K
__global__ __launch_bounds__(256) void k2_prep(const float* __restrict__ s1_raw,
                                               const float* __restrict__ s2_raw,
                                               float* __restrict__ s2k,
                                               float2* __restrict__ row2) {
    __shared__ float red[256];
    int tid = threadIdx.x;
    float m = -3.0e38f;
    for (int j = tid; j < N_NODES; j += 256) m = fmaxf(m, s2_raw[j]);
    red[tid] = m;
    __syncthreads();
    for (int s = 128; s > 0; s >>= 1) {
        if (tid < s) red[tid] = fmaxf(red[tid], red[tid + s]);
        __syncthreads();
    }
    float M2 = red[0];
    int i = blockIdx.x * 256 + tid;
    float s1 = s1_raw[i];
    float u = s1 + M2;
    float mi = fmaxf(u, 0.2f * u);
    row2[i] = make_float2((s1 - mi) * LOG2E, -0.8f * mi * LOG2E);
    s2k[i] = s2_raw[i] * LOG2E;
}

// K3 v6: fused pack+flash-GAT partials. Grid 512 = 128 rowgroups (64 rows) x 4 jq.
// 4 waves: (rq 0..1) x (ch 0..1); wave owns 32 rows (dual A-frag) x 128 cols.
// Per iter: raw adj slab for kk+1 loaded->packed->ds_write (double-buffered mask
// dwords); hTf chunk double-buffered via global_load_lds; every B-tile ds_read
// feeds TWO mfma (halved LDS traffic). adj is read exactly once grid-wide.
__global__ __launch_bounds__(256, 2) void k3_flash(const int* __restrict__ adj,
                                                   const unsigned short* __restrict__ hTf,
                                                   const float* __restrict__ s2k,
                                                   const float2* __restrict__ row2,
                                                   float* __restrict__ pout,
                                                   float* __restrict__ rowpart) {
    __shared__ __align__(16) unsigned short tiles[2][8192];  // 32 KB
    __shared__ uint32_t lmaskD[2][64];                       // 512 B, dword per (buf,row)
    __shared__ __align__(16) float ls2k[2048];               // 8 KB

    int tid = threadIdx.x;
    int w = tid >> 6, lane = tid & 63;
    int c = lane & 15, g = lane >> 4;
    int ch = w & 1, rq = w >> 1;
    int jq = blockIdx.x & 3;
    int rg = blockIdx.x >> 2;
    int rowbase = rg * 64 + rq * 32;

    // mask-stage thread mapping: 8 ints -> 1 byte
    int mrow = tid >> 2;          // block-local row 0..63
    int mg8 = tid & 3;            // byte within dword
    const int* adjbase = adj + (size_t)(rg * 64 + mrow) * N_NODES + jq * 2048 + mg8 * 8;

    // ---- prologue ----
    *(float4*)&ls2k[tid * 8]     = *(const float4*)(s2k + jq * 2048 + tid * 8);
    *(float4*)&ls2k[tid * 8 + 4] = *(const float4*)(s2k + jq * 2048 + tid * 8 + 4);
    {   // tiles for kk=0
        int jc = jq * 64;
#pragma unroll
        for (int q = 0; q < 4; ++q) {
            int ti = w * 4 + q;
            const unsigned short* src = hTf + (size_t)jc * 8192 + (size_t)(ti * 64 + lane) * 8;
            __builtin_amdgcn_global_load_lds(
                (const __attribute__((address_space(1))) uint32_t*)src,
                (__attribute__((address_space(3))) uint32_t*)(&tiles[0][ti * 512]), 16, 0, 0);
        }
    }
    {   // masks for kk=0
        int4 v0 = *(const int4*)(adjbase);
        int4 v1 = *(const int4*)(adjbase + 4);
        unsigned b = (unsigned)(v0.x != 0) | ((unsigned)(v0.y != 0) << 1)
                   | ((unsigned)(v0.z != 0) << 2) | ((unsigned)(v0.w != 0) << 3)
                   | ((unsigned)(v1.x != 0) << 4) | ((unsigned)(v1.y != 0) << 5)
                   | ((unsigned)(v1.z != 0) << 6) | ((unsigned)(v1.w != 0) << 7);
        ((unsigned char*)&lmaskD[0][mrow])[mg8] = (unsigned char)b;
    }

    float2 rc0 = row2[rowbase + c];
    float2 rc1 = row2[rowbase + 16 + c];
    float a_row0 = rc0.x, m8_0 = rc0.y;
    float a_row1 = rc1.x, m8_1 = rc1.y;

    f32x4 acc0[8], acc1[8];
#pragma unroll
    for (int t = 0; t < 8; ++t) { acc0[t] = (f32x4){0,0,0,0}; acc1[t] = (f32x4){0,0,0,0}; }
    float lacc0 = 0.f, lacc1 = 0.f;

#pragma unroll 2
    for (int kk = 0; kk < 64; ++kk) {
        int cur = kk & 1;
        __syncthreads();   // drains stage gll + mask pack writes for buffer cur

        int4 v0, v1;
        bool have_next = (kk < 63);
        if (have_next) {
            // A) issue hTf stage for kk+1
            int jc = jq * 64 + kk + 1;
#pragma unroll
            for (int q = 0; q < 4; ++q) {
                int ti = w * 4 + q;
                const unsigned short* src = hTf + (size_t)jc * 8192 + (size_t)(ti * 64 + lane) * 8;
                __builtin_amdgcn_global_load_lds(
                    (const __attribute__((address_space(1))) uint32_t*)src,
                    (__attribute__((address_space(3))) uint32_t*)(&tiles[cur ^ 1][ti * 512]), 16, 0, 0);
            }
            // B) issue raw adj loads for kk+1 (drained before pack below)
            v0 = *(const int4*)(adjbase + (kk + 1) * 32);
            v1 = *(const int4*)(adjbase + (kk + 1) * 32 + 4);
        }

        // C) score compute for 2 row-sets x 8 js
        uint32_t md0 = lmaskD[cur][rq * 32 + c];
        uint32_t md1 = lmaskD[cur][rq * 32 + 16 + c];
        uint32_t mb0 = (md0 >> (8 * g)) & 0xFFu;
        uint32_t mb1 = (md1 >> (8 * g)) & 0xFFu;
        const float* sp = &ls2k[kk * 32 + 8 * g];
        float4 s0 = *(const float4*)sp;
        float4 s1v = *(const float4*)(sp + 4);
        float sv[8] = {s0.x, s0.y, s0.z, s0.w, s1v.x, s1v.y, s1v.z, s1v.w};
        b16x8 af0, af1;
#pragma unroll
        for (int e = 0; e < 8; ++e) {
            float va = a_row0 + sv[e];
            float vb = __builtin_fmaf(va, 0.2f, m8_0);
            float p0 = (mb0 & (1u << e)) ? __builtin_amdgcn_exp2f(fmaxf(va, vb)) : 0.f;
            lacc0 += p0;
            af0[e] = (__bf16)p0;
            float vc = a_row1 + sv[e];
            float vd = __builtin_fmaf(vc, 0.2f, m8_1);
            float p1 = (mb1 & (1u << e)) ? __builtin_amdgcn_exp2f(fmaxf(vc, vd)) : 0.f;
            lacc1 += p1;
            af1[e] = (__bf16)p1;
        }

        // D) 8 shared B-tile reads, 16 mfma
        const unsigned short* tb = &tiles[cur][ch * 8 * 512];
#pragma unroll
        for (int t = 0; t < 8; ++t) {
            b16x8 bf = __builtin_bit_cast(b16x8, *(const u16x8v*)(tb + t * 512 + lane * 8));
            acc0[t] = __builtin_amdgcn_mfma_f32_16x16x32_bf16(af0, bf, acc0[t], 0, 0, 0);
            acc1[t] = __builtin_amdgcn_mfma_f32_16x16x32_bf16(af1, bf, acc1[t], 0, 0, 0);
        }

        // E) pack + write next mask buffer (loads from B drained here)
        if (have_next) {
            unsigned b = (unsigned)(v0.x != 0) | ((unsigned)(v0.y != 0) << 1)
                       | ((unsigned)(v0.z != 0) << 2) | ((unsigned)(v0.w != 0) << 3)
                       | ((unsigned)(v1.x != 0) << 4) | ((unsigned)(v1.y != 0) << 5)
                       | ((unsigned)(v1.z != 0) << 6) | ((unsigned)(v1.w != 0) << 7);
            ((unsigned char*)&lmaskD[cur ^ 1][mrow])[mg8] = (unsigned char)b;
        }
    }

    // partial row sums over this j-quarter
    float l0 = lacc0 + __shfl_xor(lacc0, 16); l0 += __shfl_xor(l0, 32);
    float l1 = lacc1 + __shfl_xor(lacc1, 16); l1 += __shfl_xor(l1, 32);
    if (ch == 0 && g == 0) {
        rowpart[jq * N_NODES + rowbase + c] = l0;
        rowpart[jq * N_NODES + rowbase + 16 + c] = l1;
    }

#pragma unroll
    for (int r = 0; r < 4; ++r) {
        int grow0 = rowbase + 4 * g + r;        // C layout: row=(lane>>4)*4+reg
        int grow1 = grow0 + 16;
#pragma unroll
        for (int t = 0; t < 8; ++t) {
            pout[((size_t)jq * N_NODES + grow0) * OUT_FEAT + ch * 128 + 16 * t + c] = acc0[t][r];
            pout[((size_t)jq * N_NODES + grow1) * OUT_FEAT + ch * 128 + 16 * t + c] = acc1[t][r];
        }
    }
}

// K4: out = elu( (sum_q pout[q]) / (sum_q rowpart[q]) ).
__global__ __launch_bounds__(256) void k4_reduce(const float* __restrict__ pout,
                                                 const float* __restrict__ rowpart,
                                                 float* __restrict__ out) {
    int t = blockIdx.x * 256 + threadIdx.x;
    int row = t >> 8;
    float s = 0.f, l = 0.f;
#pragma unroll
    for (int q = 0; q < 4; ++q) {
        s += pout[(size_t)q * N_NODES * OUT_FEAT + t];
        l += rowpart[q * N_NODES + row];
    }
    float inv = (l > 0.f) ? 1.0f / l : 0.f;
    float x = s * inv;
    out[t] = (x > 0.f) ? x : (__builtin_amdgcn_exp2f(x * LOG2E) - 1.0f);
}

extern "C" void kernel_launch(void* const* d_in, const int* in_sizes, int n_in,
                              void* d_out, int out_size, void* d_ws, size_t ws_size,
                              hipStream_t stream) {
    const float* input = (const float*)d_in[0];
    const int* adj = (const int*)d_in[1];
    const float* W = (const float*)d_in[2];
    const float* a_vec = (const float*)d_in[3];
    float* out = (float*)d_out;

    char* ws = (char*)d_ws;
    unsigned short* Wt  = (unsigned short*)(ws);                 // 256 KB
    unsigned short* hTf = (unsigned short*)(ws + 262144);        // 4 MB
    float*  s2k     = (float*)(ws + 4456448);                    // 32 KB
    float2* row2    = (float2*)(ws + 4489216);                   // 64 KB
    float*  s1_raw  = (float*)(ws + 4554752);                    // 32 KB
    float*  s2_raw  = (float*)(ws + 4587520);                    // 32 KB
    float*  rowpart = (float*)(ws + 13008896);                   // 128 KB
    float*  pout    = (float*)(ws + 13139968);                   // 32 MB

    hipLaunchKernelGGL(k0_transpose_w, dim3(512), dim3(256), 0, stream, W, Wt);
    hipLaunchKernelGGL(k1_hgemm, dim3(N_NODES / 64), dim3(256), 0, stream,
                       input, Wt, a_vec, hTf, s1_raw, s2_raw);
    hipLaunchKernelGGL(k2_prep, dim3(32), dim3(256), 0, stream, s1_raw, s2_raw, s2k, row2);
    hipLaunchKernelGGL(k3_flash, dim3(512), dim3(256), 0, stream,
                       adj, hTf, s2k, row2, pout, rowpart);
    hipLaunchKernelGGL(k4_reduce, dim3(N_NODES * OUT_FEAT / 256), dim3(256), 0, stream,
                       pout, rowpart, out);
}

// Round 8
// 174.237 us; speedup vs baseline: 1.0195x; 1.0195x over previous
//
#include <hip/hip_runtime.h>
#include <stdint.h>

#define N_NODES 8192
#define IN_FEAT 512
#define OUT_FEAT 256
#define LOG2E 1.4426950408889634f

typedef __bf16 b16x8 __attribute__((ext_vector_type(8)));
typedef unsigned short u16x8v __attribute__((ext_vector_type(8)));
typedef float f32x4 __attribute__((ext_vector_type(4)));

static __device__ __forceinline__ unsigned short f2bf(float f) {
    union { float f; uint32_t u; } v; v.f = f;
    uint32_t r = v.u + 0x7FFFu + ((v.u >> 16) & 1u);
    return (unsigned short)(r >> 16);
}

// K0: Wt[c][k] = bf16(W[k][c])  (256 x 512)
__global__ __launch_bounds__(256) void k0_transpose_w(const float* __restrict__ W,
                                                      unsigned short* __restrict__ Wt) {
    int tid = blockIdx.x * 256 + threadIdx.x;
    int c = tid & (OUT_FEAT - 1);
    int k = tid >> 8;
    Wt[(size_t)c * IN_FEAT + k] = f2bf(W[(size_t)k * OUT_FEAT + c]);
}

// K1: h = X @ W via bf16 MFMA. Writes hTf in MFMA-B-fragment order:
// hTf[((chunk*16 + t)*64 + lane)*8 + e] = bf16(h[chunk*32 + (lane>>4)*8 + e][16t + (lane&15)])
__global__ __launch_bounds__(256) void k1_hgemm(const float* __restrict__ input,
                                                const unsigned short* __restrict__ Wt,
                                                const float* __restrict__ a_vec,
                                                unsigned short* __restrict__ hTf,
                                                float* __restrict__ s1_raw,
                                                float* __restrict__ s2_raw) {
    int tid = threadIdx.x;
    int lane = tid & 63;
    int c = lane & 15, g = lane >> 4;
    int r0 = blockIdx.x * 64 + (tid >> 6) * 16;
    f32x4 acc[16];
#pragma unroll
    for (int t = 0; t < 16; ++t) acc[t] = (f32x4){0.f, 0.f, 0.f, 0.f};
    const float* arow = input + (size_t)(r0 + c) * IN_FEAT;
#pragma unroll 1
    for (int kk = 0; kk < IN_FEAT / 32; ++kk) {
        int kb = kk * 32 + 8 * g;
        float4 x0 = *(const float4*)(arow + kb);
        float4 x1 = *(const float4*)(arow + kb + 4);
        u16x8v au;
        au[0] = f2bf(x0.x); au[1] = f2bf(x0.y); au[2] = f2bf(x0.z); au[3] = f2bf(x0.w);
        au[4] = f2bf(x1.x); au[5] = f2bf(x1.y); au[6] = f2bf(x1.z); au[7] = f2bf(x1.w);
        b16x8 af = __builtin_bit_cast(b16x8, au);
#pragma unroll
        for (int t = 0; t < 16; ++t) {
            b16x8 bf = __builtin_bit_cast(b16x8,
                *(const u16x8v*)(Wt + (size_t)(16 * t + c) * IN_FEAT + kb));
            acc[t] = __builtin_amdgcn_mfma_f32_16x16x32_bf16(af, bf, acc[t], 0, 0, 0);
        }
    }
    float a1v[16], a2v[16];
#pragma unroll
    for (int t = 0; t < 16; ++t) {
        a1v[t] = a_vec[16 * t + c];
        a2v[t] = a_vec[OUT_FEAT + 16 * t + c];
    }
#pragma unroll
    for (int r = 0; r < 4; ++r) {
        float s1p = 0.f, s2p = 0.f;
#pragma unroll
        for (int t = 0; t < 16; ++t) { s1p += acc[t][r] * a1v[t]; s2p += acc[t][r] * a2v[t]; }
#pragma unroll
        for (int m = 1; m <= 8; m <<= 1) { s1p += __shfl_xor(s1p, m); s2p += __shfl_xor(s2p, m); }
        if (c == 0) {
            int row = r0 + 4 * g + r;
            s1_raw[row] = s1p;
            s2_raw[row] = s2p;
        }
    }
    int chunk = r0 >> 5;
    int lp = ((r0 & 16) >> 3) + (g >> 1);
    int e0 = 4 * (g & 1);
#pragma unroll
    for (int t = 0; t < 16; ++t) {
        ushort4 pk;
        pk.x = f2bf(acc[t][0]); pk.y = f2bf(acc[t][1]);
        pk.z = f2bf(acc[t][2]); pk.w = f2bf(acc[t][3]);
        *(ushort4*)(hTf + ((size_t)(chunk * 16 + t) * 64 + lp * 16 + c) * 8 + e0) = pk;
    }
}

// K2: M2 = max(s2); per-row constants a_row=(s1-m)*K, m8=-0.8*m*K; s2k=s2*K
__global__ __launch_bounds__(256) void k2_prep(const float* __restrict__ s1_raw,
                                               const float* __restrict__ s2_raw,
                                               float* __restrict__ s2k,
                                               float2* __restrict__ row2) {
    __shared__ float red[256];
    int tid = threadIdx.x;
    float m = -3.0e38f;
    for (int j = tid; j < N_NODES; j += 256) m = fmaxf(m, s2_raw[j]);
    red[tid] = m;
    __syncthreads();
    for (int s = 128; s > 0; s >>= 1) {
        if (tid < s) red[tid] = fmaxf(red[tid], red[tid + s]);
        __syncthreads();
    }
    float M2 = red[0];
    int i = blockIdx.x * 256 + tid;
    float s1 = s1_raw[i];
    float u = s1 + M2;
    float mi = fmaxf(u, 0.2f * u);
    row2[i] = make_float2((s1 - mi) * LOG2E, -0.8f * mi * LOG2E);
    s2k[i] = s2_raw[i] * LOG2E;
}

// K3 v7: fused pack+flash-GAT, depth-2 adj register pipeline.
// Grid 512 = 128 rowgroups (64 rows) x 4 jq. 4 waves: (rq 0..1) x (ch 0..1),
// wave owns 32 rows (dual A-frag) x 128 cols.
// Iter kk: [issue adj loads for kk+2] [issue gll tile stage kk+1]
//          [score+MFMA from buffers cur] [pack adj regs (issued kk-1) -> mask kk+1].
// Pack consumes the OLDEST outstanding VMEM -> counted vmcnt, gll stay in
// flight across the barrier (the R7 bug was vmcnt(0) draining them).
__global__ __launch_bounds__(256, 3) void k3_flash(const int* __restrict__ adj,
                                                   const unsigned short* __restrict__ hTf,
                                                   const float* __restrict__ s2k,
                                                   const float2* __restrict__ row2,
                                                   float* __restrict__ pout,
                                                   float* __restrict__ rowpart) {
    __shared__ __align__(16) unsigned short tiles[2][8192];  // 32 KB
    __shared__ uint32_t lmaskD[2][64];                       // 512 B
    __shared__ __align__(16) float ls2k[2048];               // 8 KB

    int tid = threadIdx.x;
    int w = tid >> 6, lane = tid & 63;
    int c = lane & 15, g = lane >> 4;
    int ch = w & 1, rq = w >> 1;
    int jq = blockIdx.x & 3;
    int rg = blockIdx.x >> 2;
    int rowbase = rg * 64 + rq * 32;

    // mask-stage thread mapping: 8 ints -> 1 byte
    int mrow = tid >> 2;          // block-local row 0..63
    int mg8 = tid & 3;            // byte within dword
    const int* adjbase = adj + (size_t)(rg * 64 + mrow) * N_NODES + jq * 2048 + mg8 * 8;

    // ---- prologue ----
    *(float4*)&ls2k[tid * 8]     = *(const float4*)(s2k + jq * 2048 + tid * 8);
    *(float4*)&ls2k[tid * 8 + 4] = *(const float4*)(s2k + jq * 2048 + tid * 8 + 4);
    {   // masks for kk=0 (synchronous pack)
        int4 v0 = *(const int4*)(adjbase);
        int4 v1 = *(const int4*)(adjbase + 4);
        unsigned b = (unsigned)(v0.x != 0) | ((unsigned)(v0.y != 0) << 1)
                   | ((unsigned)(v0.z != 0) << 2) | ((unsigned)(v0.w != 0) << 3)
                   | ((unsigned)(v1.x != 0) << 4) | ((unsigned)(v1.y != 0) << 5)
                   | ((unsigned)(v1.z != 0) << 6) | ((unsigned)(v1.w != 0) << 7);
        ((unsigned char*)&lmaskD[0][mrow])[mg8] = (unsigned char)b;
    }
    // in-flight adj regs for chunk kk=1 (consumed at E of kk=0)
    int4 va0 = *(const int4*)(adjbase + 32);
    int4 va1 = *(const int4*)(adjbase + 36);
    {   // tiles for kk=0
        int jc = jq * 64;
#pragma unroll
        for (int q = 0; q < 4; ++q) {
            int ti = w * 4 + q;
            const unsigned short* src = hTf + (size_t)jc * 8192 + (size_t)(ti * 64 + lane) * 8;
            __builtin_amdgcn_global_load_lds(
                (const __attribute__((address_space(1))) uint32_t*)src,
                (__attribute__((address_space(3))) uint32_t*)(&tiles[0][ti * 512]), 16, 0, 0);
        }
    }

    float2 rc0 = row2[rowbase + c];
    float2 rc1 = row2[rowbase + 16 + c];
    float a_row0 = rc0.x, m8_0 = rc0.y;
    float a_row1 = rc1.x, m8_1 = rc1.y;

    f32x4 acc0[8], acc1[8];
#pragma unroll
    for (int t = 0; t < 8; ++t) { acc0[t] = (f32x4){0,0,0,0}; acc1[t] = (f32x4){0,0,0,0}; }
    float lacc0 = 0.f, lacc1 = 0.f;

#pragma unroll 2
    for (int kk = 0; kk < 64; ++kk) {
        int cur = kk & 1;
        __syncthreads();   // drains gll into tiles[cur] + mask writes into lmaskD[cur]

        // A') adj loads for chunk kk+2 (oldest-first discipline: issue before gll)
        int4 vb0, vb1;
        if (kk < 62) {
            vb0 = *(const int4*)(adjbase + (kk + 2) * 32);
            vb1 = *(const int4*)(adjbase + (kk + 2) * 32 + 4);
        }
        // A) gll tile stage for kk+1
        if (kk < 63) {
            int jc = jq * 64 + kk + 1;
#pragma unroll
            for (int q = 0; q < 4; ++q) {
                int ti = w * 4 + q;
                const unsigned short* src = hTf + (size_t)jc * 8192 + (size_t)(ti * 64 + lane) * 8;
                __builtin_amdgcn_global_load_lds(
                    (const __attribute__((address_space(1))) uint32_t*)src,
                    (__attribute__((address_space(3))) uint32_t*)(&tiles[cur ^ 1][ti * 512]), 16, 0, 0);
            }
        }

        // C) score compute for 2 row-sets x 8 js
        uint32_t md0 = lmaskD[cur][rq * 32 + c];
        uint32_t md1 = lmaskD[cur][rq * 32 + 16 + c];
        uint32_t mb0 = (md0 >> (8 * g)) & 0xFFu;
        uint32_t mb1 = (md1 >> (8 * g)) & 0xFFu;
        const float* sp = &ls2k[kk * 32 + 8 * g];
        float4 s0 = *(const float4*)sp;
        float4 s1v = *(const float4*)(sp + 4);
        float sv[8] = {s0.x, s0.y, s0.z, s0.w, s1v.x, s1v.y, s1v.z, s1v.w};
        b16x8 af0, af1;
#pragma unroll
        for (int e = 0; e < 8; ++e) {
            float va = a_row0 + sv[e];
            float vb = __builtin_fmaf(va, 0.2f, m8_0);
            float p0 = (mb0 & (1u << e)) ? __builtin_amdgcn_exp2f(fmaxf(va, vb)) : 0.f;
            lacc0 += p0;
            af0[e] = (__bf16)p0;
            float vc = a_row1 + sv[e];
            float vd = __builtin_fmaf(vc, 0.2f, m8_1);
            float p1 = (mb1 & (1u << e)) ? __builtin_amdgcn_exp2f(fmaxf(vc, vd)) : 0.f;
            lacc1 += p1;
            af1[e] = (__bf16)p1;
        }

        // D) 8 shared B-tile reads, 16 mfma
        const unsigned short* tb = &tiles[cur][ch * 8 * 512];
#pragma unroll
        for (int t = 0; t < 8; ++t) {
            b16x8 bf = __builtin_bit_cast(b16x8, *(const u16x8v*)(tb + t * 512 + lane * 8));
            acc0[t] = __builtin_amdgcn_mfma_f32_16x16x32_bf16(af0, bf, acc0[t], 0, 0, 0);
            acc1[t] = __builtin_amdgcn_mfma_f32_16x16x32_bf16(af1, bf, acc1[t], 0, 0, 0);
        }

        // E) pack regs issued at kk-1 (chunk kk+1): OLDEST outstanding -> vmcnt(N>0)
        if (kk < 63) {
            unsigned b = (unsigned)(va0.x != 0) | ((unsigned)(va0.y != 0) << 1)
                       | ((unsigned)(va0.z != 0) << 2) | ((unsigned)(va0.w != 0) << 3)
                       | ((unsigned)(va1.x != 0) << 4) | ((unsigned)(va1.y != 0) << 5)
                       | ((unsigned)(va1.z != 0) << 6) | ((unsigned)(va1.w != 0) << 7);
            ((unsigned char*)&lmaskD[cur ^ 1][mrow])[mg8] = (unsigned char)b;
            va0 = vb0; va1 = vb1;
        }
    }

    // partial row sums over this j-quarter
    float l0 = lacc0 + __shfl_xor(lacc0, 16); l0 += __shfl_xor(l0, 32);
    float l1 = lacc1 + __shfl_xor(lacc1, 16); l1 += __shfl_xor(l1, 32);
    if (ch == 0 && g == 0) {
        rowpart[jq * N_NODES + rowbase + c] = l0;
        rowpart[jq * N_NODES + rowbase + 16 + c] = l1;
    }

#pragma unroll
    for (int r = 0; r < 4; ++r) {
        int grow0 = rowbase + 4 * g + r;        // C layout: row=(lane>>4)*4+reg
        int grow1 = grow0 + 16;
#pragma unroll
        for (int t = 0; t < 8; ++t) {
            pout[((size_t)jq * N_NODES + grow0) * OUT_FEAT + ch * 128 + 16 * t + c] = acc0[t][r];
            pout[((size_t)jq * N_NODES + grow1) * OUT_FEAT + ch * 128 + 16 * t + c] = acc1[t][r];
        }
    }
}

// K4: out = elu( (sum_q pout[q]) / (sum_q rowpart[q]) ).
__global__ __launch_bounds__(256) void k4_reduce(const float* __restrict__ pout,
                                                 const float* __restrict__ rowpart,
                                                 float* __restrict__ out) {
    int t = blockIdx.x * 256 + threadIdx.x;
    int row = t >> 8;
    float s = 0.f, l = 0.f;
#pragma unroll
    for (int q = 0; q < 4; ++q) {
        s += pout[(size_t)q * N_NODES * OUT_FEAT + t];
        l += rowpart[q * N_NODES + row];
    }
    float inv = (l > 0.f) ? 1.0f / l : 0.f;
    float x = s * inv;
    out[t] = (x > 0.f) ? x : (__builtin_amdgcn_exp2f(x * LOG2E) - 1.0f);
}

extern "C" void kernel_launch(void* const* d_in, const int* in_sizes, int n_in,
                              void* d_out, int out_size, void* d_ws, size_t ws_size,
                              hipStream_t stream) {
    const float* input = (const float*)d_in[0];
    const int* adj = (const int*)d_in[1];
    const float* W = (const float*)d_in[2];
    const float* a_vec = (const float*)d_in[3];
    float* out = (float*)d_out;

    char* ws = (char*)d_ws;
    unsigned short* Wt  = (unsigned short*)(ws);                 // 256 KB
    unsigned short* hTf = (unsigned short*)(ws + 262144);        // 4 MB
    float*  s2k     = (float*)(ws + 4456448);                    // 32 KB
    float2* row2    = (float2*)(ws + 4489216);                   // 64 KB
    float*  s1_raw  = (float*)(ws + 4554752);                    // 32 KB
    float*  s2_raw  = (float*)(ws + 4587520);                    // 32 KB
    float*  rowpart = (float*)(ws + 13008896);                   // 128 KB
    float*  pout    = (float*)(ws + 13139968);                   // 32 MB

    hipLaunchKernelGGL(k0_transpose_w, dim3(512), dim3(256), 0, stream, W, Wt);
    hipLaunchKernelGGL(k1_hgemm, dim3(N_NODES / 64), dim3(256), 0, stream,
                       input, Wt, a_vec, hTf, s1_raw, s2_raw);
    hipLaunchKernelGGL(k2_prep, dim3(32), dim3(256), 0, stream, s1_raw, s2_raw, s2k, row2);
    hipLaunchKernelGGL(k3_flash, dim3(512), dim3(256), 0, stream,
                       adj, hTf, s2k, row2, pout, rowpart);
    hipLaunchKernelGGL(k4_reduce, dim3(N_NODES * OUT_FEAT / 256), dim3(256), 0, stream,
                       pout, rowpart, out);
}

// Round 9
// 168.368 us; speedup vs baseline: 1.0550x; 1.0349x over previous
//
#include <hip/hip_runtime.h>
#include <stdint.h>

#define N_NODES 8192
#define IN_FEAT 512
#define OUT_FEAT 256
#define LOG2E 1.4426950408889634f

typedef __bf16 b16x8 __attribute__((ext_vector_type(8)));
typedef unsigned short u16x8v __attribute__((ext_vector_type(8)));
typedef float f32x4 __attribute__((ext_vector_type(4)));

static __device__ __forceinline__ unsigned short f2bf(float f) {
    union { float f; uint32_t u; } v; v.f = f;
    uint32_t r = v.u + 0x7FFFu + ((v.u >> 16) & 1u);
    return (unsigned short)(r >> 16);
}

// K0: Wt[c][k] = bf16(W[k][c])  (256 x 512)
__global__ __launch_bounds__(256) void k0_transpose_w(const float* __restrict__ W,
                                                      unsigned short* __restrict__ Wt) {
    int tid = blockIdx.x * 256 + threadIdx.x;
    int c = tid & (OUT_FEAT - 1);
    int k = tid >> 8;
    Wt[(size_t)c * IN_FEAT + k] = f2bf(W[(size_t)k * OUT_FEAT + c]);
}

// K1: h = X @ W via bf16 MFMA. Writes hTf in MFMA-B-fragment order.
__global__ __launch_bounds__(256) void k1_hgemm(const float* __restrict__ input,
                                                const unsigned short* __restrict__ Wt,
                                                const float* __restrict__ a_vec,
                                                unsigned short* __restrict__ hTf,
                                                float* __restrict__ s1_raw,
                                                float* __restrict__ s2_raw) {
    int tid = threadIdx.x;
    int lane = tid & 63;
    int c = lane & 15, g = lane >> 4;
    int r0 = blockIdx.x * 64 + (tid >> 6) * 16;
    f32x4 acc[16];
#pragma unroll
    for (int t = 0; t < 16; ++t) acc[t] = (f32x4){0.f, 0.f, 0.f, 0.f};
    const float* arow = input + (size_t)(r0 + c) * IN_FEAT;
#pragma unroll 1
    for (int kk = 0; kk < IN_FEAT / 32; ++kk) {
        int kb = kk * 32 + 8 * g;
        float4 x0 = *(const float4*)(arow + kb);
        float4 x1 = *(const float4*)(arow + kb + 4);
        u16x8v au;
        au[0] = f2bf(x0.x); au[1] = f2bf(x0.y); au[2] = f2bf(x0.z); au[3] = f2bf(x0.w);
        au[4] = f2bf(x1.x); au[5] = f2bf(x1.y); au[6] = f2bf(x1.z); au[7] = f2bf(x1.w);
        b16x8 af = __builtin_bit_cast(b16x8, au);
#pragma unroll
        for (int t = 0; t < 16; ++t) {
            b16x8 bf = __builtin_bit_cast(b16x8,
                *(const u16x8v*)(Wt + (size_t)(16 * t + c) * IN_FEAT + kb));
            acc[t] = __builtin_amdgcn_mfma_f32_16x16x32_bf16(af, bf, acc[t], 0, 0, 0);
        }
    }
    float a1v[16], a2v[16];
#pragma unroll
    for (int t = 0; t < 16; ++t) {
        a1v[t] = a_vec[16 * t + c];
        a2v[t] = a_vec[OUT_FEAT + 16 * t + c];
    }
#pragma unroll
    for (int r = 0; r < 4; ++r) {
        float s1p = 0.f, s2p = 0.f;
#pragma unroll
        for (int t = 0; t < 16; ++t) { s1p += acc[t][r] * a1v[t]; s2p += acc[t][r] * a2v[t]; }
#pragma unroll
        for (int m = 1; m <= 8; m <<= 1) { s1p += __shfl_xor(s1p, m); s2p += __shfl_xor(s2p, m); }
        if (c == 0) {
            int row = r0 + 4 * g + r;
            s1_raw[row] = s1p;
            s2_raw[row] = s2p;
        }
    }
    int chunk = r0 >> 5;
    int lp = ((r0 & 16) >> 3) + (g >> 1);
    int e0 = 4 * (g & 1);
#pragma unroll
    for (int t = 0; t < 16; ++t) {
        ushort4 pk;
        pk.x = f2bf(acc[t][0]); pk.y = f2bf(acc[t][1]);
        pk.z = f2bf(acc[t][2]); pk.w = f2bf(acc[t][3]);
        *(ushort4*)(hTf + ((size_t)(chunk * 16 + t) * 64 + lp * 16 + c) * 8 + e0) = pk;
    }
}

// K2: M2 = max(s2); per-row constants a_row=(s1-m)*K, m8=-0.8*m*K; s2k=s2*K
__global__ __launch_bounds__(256) void k2_prep(const float* __restrict__ s1_raw,
                                               const float* __restrict__ s2_raw,
                                               float* __restrict__ s2k,
                                               float2* __restrict__ row2) {
    __shared__ float red[256];
    int tid = threadIdx.x;
    float m = -3.0e38f;
    for (int j = tid; j < N_NODES; j += 256) m = fmaxf(m, s2_raw[j]);
    red[tid] = m;
    __syncthreads();
    for (int s = 128; s > 0; s >>= 1) {
        if (tid < s) red[tid] = fmaxf(red[tid], red[tid + s]);
        __syncthreads();
    }
    float M2 = red[0];
    int i = blockIdx.x * 256 + tid;
    float s1 = s1_raw[i];
    float u = s1 + M2;
    float mi = fmaxf(u, 0.2f * u);
    row2[i] = make_float2((s1 - mi) * LOG2E, -0.8f * mi * LOG2E);
    s2k[i] = s2_raw[i] * LOG2E;
}

// K3 v8: fused pack+flash-GAT with RAW s_barrier + counted vmcnt (T4).
// Per-iter VMEM ledger (order pinned by sched_barrier):
//   entry: {adjL[kk+1]:2}  ->  +gllT[kk+1]:4  ->  +adjL[kk+2]:2   (8 total)
//   pack E consumes adjL[kk+1] (oldest; compiler emits counted vmcnt(6))
//   pre-barrier asm vmcnt(2): retires own gll, adj loads STAY IN FLIGHT.
// Tail iters 62/63 peeled (no OOB prefetch; vmcnt(0) drain there is fine).
__global__ __launch_bounds__(256, 3) void k3_flash(const int* __restrict__ adj,
                                                   const unsigned short* __restrict__ hTf,
                                                   const float* __restrict__ s2k,
                                                   const float2* __restrict__ row2,
                                                   float* __restrict__ pout,
                                                   float* __restrict__ rowpart) {
    __shared__ __align__(16) unsigned short tiles[2][8192];  // 32 KB
    __shared__ uint32_t lmaskD[2][64];                       // 512 B
    __shared__ __align__(16) float ls2k[2048];               // 8 KB

    int tid = threadIdx.x;
    int w = tid >> 6, lane = tid & 63;
    int c = lane & 15, g = lane >> 4;
    int ch = w & 1, rq = w >> 1;
    int jq = blockIdx.x & 3;
    int rg = blockIdx.x >> 2;
    int rowbase = rg * 64 + rq * 32;

    int mrow = tid >> 2;          // block-local row 0..63
    int mg8 = tid & 3;            // byte within dword
    const int* adjbase = adj + (size_t)(rg * 64 + mrow) * N_NODES + jq * 2048 + mg8 * 8;

    // ---- prologue ----
    *(float4*)&ls2k[tid * 8]     = *(const float4*)(s2k + jq * 2048 + tid * 8);
    *(float4*)&ls2k[tid * 8 + 4] = *(const float4*)(s2k + jq * 2048 + tid * 8 + 4);
    {   // masks for chunk 0 (synchronous pack; compiler emits its own counted waits)
        int4 v0 = *(const int4*)(adjbase);
        int4 v1 = *(const int4*)(adjbase + 4);
        unsigned b = (unsigned)(v0.x != 0) | ((unsigned)(v0.y != 0) << 1)
                   | ((unsigned)(v0.z != 0) << 2) | ((unsigned)(v0.w != 0) << 3)
                   | ((unsigned)(v1.x != 0) << 4) | ((unsigned)(v1.y != 0) << 5)
                   | ((unsigned)(v1.z != 0) << 6) | ((unsigned)(v1.w != 0) << 7);
        ((unsigned char*)&lmaskD[0][mrow])[mg8] = (unsigned char)b;
    }
    __builtin_amdgcn_sched_barrier(0);
    {   // gll tile 0 (must be OLDER than adjL[1])
        int jc = jq * 64;
#pragma unroll
        for (int q = 0; q < 4; ++q) {
            int ti = w * 4 + q;
            const unsigned short* src = hTf + (size_t)jc * 8192 + (size_t)(ti * 64 + lane) * 8;
            __builtin_amdgcn_global_load_lds(
                (const __attribute__((address_space(1))) uint32_t*)src,
                (__attribute__((address_space(3))) uint32_t*)(&tiles[0][ti * 512]), 16, 0, 0);
        }
    }
    __builtin_amdgcn_sched_barrier(0);
    // adjL[1] in-flight regs (chunk 1), newest
    int4 va0 = *(const int4*)(adjbase + 32);
    int4 va1 = *(const int4*)(adjbase + 36);
    __builtin_amdgcn_sched_barrier(0);
    asm volatile("s_waitcnt vmcnt(2) lgkmcnt(0)" ::: "memory");
    __builtin_amdgcn_sched_barrier(0);
    __builtin_amdgcn_s_barrier();
    __builtin_amdgcn_sched_barrier(0);

    float2 rc0 = row2[rowbase + c];
    float2 rc1 = row2[rowbase + 16 + c];
    float a_row0 = rc0.x, m8_0 = rc0.y;
    float a_row1 = rc1.x, m8_1 = rc1.y;

    f32x4 acc0[8], acc1[8];
#pragma unroll
    for (int t = 0; t < 8; ++t) { acc0[t] = (f32x4){0,0,0,0}; acc1[t] = (f32x4){0,0,0,0}; }
    float lacc0 = 0.f, lacc1 = 0.f;

#define SCORE_AND_MFMA(CUR, KK)                                                          \
    {                                                                                    \
        uint32_t md0 = lmaskD[CUR][rq * 32 + c];                                         \
        uint32_t md1 = lmaskD[CUR][rq * 32 + 16 + c];                                    \
        uint32_t mb0 = (md0 >> (8 * g)) & 0xFFu;                                         \
        uint32_t mb1 = (md1 >> (8 * g)) & 0xFFu;                                         \
        const float* sp = &ls2k[(KK) * 32 + 8 * g];                                      \
        float4 s0 = *(const float4*)sp;                                                  \
        float4 s1v = *(const float4*)(sp + 4);                                           \
        float sv[8] = {s0.x, s0.y, s0.z, s0.w, s1v.x, s1v.y, s1v.z, s1v.w};              \
        b16x8 af0, af1;                                                                  \
        _Pragma("unroll")                                                                \
        for (int e = 0; e < 8; ++e) {                                                    \
            float va = a_row0 + sv[e];                                                   \
            float vb = __builtin_fmaf(va, 0.2f, m8_0);                                   \
            float p0 = (mb0 & (1u << e)) ? __builtin_amdgcn_exp2f(fmaxf(va, vb)) : 0.f;  \
            lacc0 += p0;                                                                 \
            af0[e] = (__bf16)p0;                                                         \
            float vc = a_row1 + sv[e];                                                   \
            float vd = __builtin_fmaf(vc, 0.2f, m8_1);                                   \
            float p1 = (mb1 & (1u << e)) ? __builtin_amdgcn_exp2f(fmaxf(vc, vd)) : 0.f;  \
            lacc1 += p1;                                                                 \
            af1[e] = (__bf16)p1;                                                         \
        }                                                                                \
        const unsigned short* tb = &tiles[CUR][ch * 8 * 512];                            \
        _Pragma("unroll")                                                                \
        for (int t = 0; t < 8; ++t) {                                                    \
            b16x8 bf = __builtin_bit_cast(b16x8, *(const u16x8v*)(tb + t * 512 + lane * 8)); \
            acc0[t] = __builtin_amdgcn_mfma_f32_16x16x32_bf16(af0, bf, acc0[t], 0, 0, 0); \
            acc1[t] = __builtin_amdgcn_mfma_f32_16x16x32_bf16(af1, bf, acc1[t], 0, 0, 0); \
        }                                                                                \
    }

#define PACK_NEXT(CURX)                                                                  \
    {                                                                                    \
        unsigned b = (unsigned)(va0.x != 0) | ((unsigned)(va0.y != 0) << 1)              \
                   | ((unsigned)(va0.z != 0) << 2) | ((unsigned)(va0.w != 0) << 3)       \
                   | ((unsigned)(va1.x != 0) << 4) | ((unsigned)(va1.y != 0) << 5)       \
                   | ((unsigned)(va1.z != 0) << 6) | ((unsigned)(va1.w != 0) << 7);      \
        ((unsigned char*)&lmaskD[(CURX) ^ 1][mrow])[mg8] = (unsigned char)b;             \
    }

#pragma unroll 2
    for (int kk = 0; kk < 62; ++kk) {
        int cur = kk & 1;
        // B: gll tile kk+1 (older)
        {
            int jc = jq * 64 + kk + 1;
#pragma unroll
            for (int q = 0; q < 4; ++q) {
                int ti = w * 4 + q;
                const unsigned short* src = hTf + (size_t)jc * 8192 + (size_t)(ti * 64 + lane) * 8;
                __builtin_amdgcn_global_load_lds(
                    (const __attribute__((address_space(1))) uint32_t*)src,
                    (__attribute__((address_space(3))) uint32_t*)(&tiles[cur ^ 1][ti * 512]), 16, 0, 0);
            }
        }
        __builtin_amdgcn_sched_barrier(0);
        // A': adj loads chunk kk+2 (newer; survive the pre-barrier vmcnt(2))
        int4 vb0 = *(const int4*)(adjbase + (kk + 2) * 32);
        int4 vb1 = *(const int4*)(adjbase + (kk + 2) * 32 + 4);
        __builtin_amdgcn_sched_barrier(0);
        // C+D: score + MFMA from buffers [cur]
        SCORE_AND_MFMA(cur, kk)
        // E: pack adjL[kk+1] -> lmaskD[cur^1] (compiler emits counted vmcnt(6))
        PACK_NEXT(cur)
        va0 = vb0; va1 = vb1;
        __builtin_amdgcn_sched_barrier(0);
        asm volatile("s_waitcnt vmcnt(2) lgkmcnt(0)" ::: "memory");
        __builtin_amdgcn_sched_barrier(0);
        __builtin_amdgcn_s_barrier();
        __builtin_amdgcn_sched_barrier(0);
    }
    // kk = 62 (cur=0): stage tile 63, no adj prefetch, full drain at end
    {
        int jc = jq * 64 + 63;
#pragma unroll
        for (int q = 0; q < 4; ++q) {
            int ti = w * 4 + q;
            const unsigned short* src = hTf + (size_t)jc * 8192 + (size_t)(ti * 64 + lane) * 8;
            __builtin_amdgcn_global_load_lds(
                (const __attribute__((address_space(1))) uint32_t*)src,
                (__attribute__((address_space(3))) uint32_t*)(&tiles[1][ti * 512]), 16, 0, 0);
        }
        __builtin_amdgcn_sched_barrier(0);
        SCORE_AND_MFMA(0, 62)
        PACK_NEXT(0)
        __builtin_amdgcn_sched_barrier(0);
        asm volatile("s_waitcnt vmcnt(0) lgkmcnt(0)" ::: "memory");
        __builtin_amdgcn_sched_barrier(0);
        __builtin_amdgcn_s_barrier();
        __builtin_amdgcn_sched_barrier(0);
    }
    // kk = 63 (cur=1): compute only
    SCORE_AND_MFMA(1, 63)

    // partial row sums over this j-quarter
    float l0 = lacc0 + __shfl_xor(lacc0, 16); l0 += __shfl_xor(l0, 32);
    float l1 = lacc1 + __shfl_xor(lacc1, 16); l1 += __shfl_xor(l1, 32);
    if (ch == 0 && g == 0) {
        rowpart[jq * N_NODES + rowbase + c] = l0;
        rowpart[jq * N_NODES + rowbase + 16 + c] = l1;
    }

#pragma unroll
    for (int r = 0; r < 4; ++r) {
        int grow0 = rowbase + 4 * g + r;        // C layout: row=(lane>>4)*4+reg
        int grow1 = grow0 + 16;
#pragma unroll
        for (int t = 0; t < 8; ++t) {
            pout[((size_t)jq * N_NODES + grow0) * OUT_FEAT + ch * 128 + 16 * t + c] = acc0[t][r];
            pout[((size_t)jq * N_NODES + grow1) * OUT_FEAT + ch * 128 + 16 * t + c] = acc1[t][r];
        }
    }
#undef SCORE_AND_MFMA
#undef PACK_NEXT
}

// K4: out = elu( (sum_q pout[q]) / (sum_q rowpart[q]) ).
__global__ __launch_bounds__(256) void k4_reduce(const float* __restrict__ pout,
                                                 const float* __restrict__ rowpart,
                                                 float* __restrict__ out) {
    int t = blockIdx.x * 256 + threadIdx.x;
    int row = t >> 8;
    float s = 0.f, l = 0.f;
#pragma unroll
    for (int q = 0; q < 4; ++q) {
        s += pout[(size_t)q * N_NODES * OUT_FEAT + t];
        l += rowpart[q * N_NODES + row];
    }
    float inv = (l > 0.f) ? 1.0f / l : 0.f;
    float x = s * inv;
    out[t] = (x > 0.f) ? x : (__builtin_amdgcn_exp2f(x * LOG2E) - 1.0f);
}

extern "C" void kernel_launch(void* const* d_in, const int* in_sizes, int n_in,
                              void* d_out, int out_size, void* d_ws, size_t ws_size,
                              hipStream_t stream) {
    const float* input = (const float*)d_in[0];
    const int* adj = (const int*)d_in[1];
    const float* W = (const float*)d_in[2];
    const float* a_vec = (const float*)d_in[3];
    float* out = (float*)d_out;

    char* ws = (char*)d_ws;
    unsigned short* Wt  = (unsigned short*)(ws);                 // 256 KB
    unsigned short* hTf = (unsigned short*)(ws + 262144);        // 4 MB
    float*  s2k     = (float*)(ws + 4456448);                    // 32 KB
    float2* row2    = (float2*)(ws + 4489216);                   // 64 KB
    float*  s1_raw  = (float*)(ws + 4554752);                    // 32 KB
    float*  s2_raw  = (float*)(ws + 4587520);                    // 32 KB
    float*  rowpart = (float*)(ws + 13008896);                   // 128 KB
    float*  pout    = (float*)(ws + 13139968);                   // 32 MB

    hipLaunchKernelGGL(k0_transpose_w, dim3(512), dim3(256), 0, stream, W, Wt);
    hipLaunchKernelGGL(k1_hgemm, dim3(N_NODES / 64), dim3(256), 0, stream,
                       input, Wt, a_vec, hTf, s1_raw, s2_raw);
    hipLaunchKernelGGL(k2_prep, dim3(32), dim3(256), 0, stream, s1_raw, s2_raw, s2k, row2);
    hipLaunchKernelGGL(k3_flash, dim3(512), dim3(256), 0, stream,
                       adj, hTf, s2k, row2, pout, rowpart);
    hipLaunchKernelGGL(k4_reduce, dim3(N_NODES * OUT_FEAT / 256), dim3(256), 0, stream,
                       pout, rowpart, out);
}